// Round 12
// baseline (41.090 us; speedup 1.0000x reference)
//
#include <hip/hip_runtime.h>
#include <hip/hip_bf16.h>
#include <math.h>

#define N 1024
#define TB 16

typedef __attribute__((ext_vector_type(8))) short short8;
typedef __attribute__((ext_vector_type(4))) short short4v;
typedef __attribute__((ext_vector_type(4))) float f32x4;

// PReLU via max/min: max(v,0) + a*min(v,0)
__device__ __forceinline__ float prelu(float v, float a) {
    return fmaxf(v, 0.f) + a * fminf(v, 0.f);
}

// f32 -> bf16 RNE via hardware cvt (pairs into v_cvt_pk_bf16_f32)
__device__ __forceinline__ short f2bf(float f) {
    return (short)__bfloat16_as_ushort(__float2bfloat16(f));
}

// One block per lower-triangle tile; processes BOTH batches (z=0,1) through the
// same LDS buffers: A0 | bar | B0 | bar | {C0 + A1} | bar | B1 | bar | C1.
// Upper-triangle zero tiles fused as a fire-and-forget prologue.
__global__ __launch_bounds__(256, 8) void precond_mfma(
    const float* __restrict__ xg, const int* __restrict__ maskg,
    const float* __restrict__ w1, const float* __restrict__ b1, const float* __restrict__ a1p,
    const float* __restrict__ w2, const float* __restrict__ b2, const float* __restrict__ a2p,
    const float* __restrict__ w3, const float* __restrict__ b3, const float* __restrict__ a3p,
    const float* __restrict__ w4, const float* __restrict__ b4p,
    float* __restrict__ out)
{
    const int tid = threadIdx.x;
    const int t   = blockIdx.x;

    // ---- triangular mapping: t -> (by, bx), bx <= by ----
    int by = (int)((sqrtf(8.0f * (float)t + 1.0f) - 1.0f) * 0.5f);
    while ((by + 1) * (by + 2) / 2 <= t) ++by;
    while (by * (by + 1) / 2 > t) --by;
    const int bx = t - by * (by + 1) / 2;
    const int ty0 = by * TB, tx0 = bx * TB;

    // ---- fused zero-fill: block t (t<2016) clears upper tile #t in BOTH batches ----
    if (t < 2016) {
        int y = (int)((sqrtf(8.0f * (float)t + 1.0f) + 1.0f) * 0.5f);
        while (y * (y - 1) / 2 > t) --y;
        while ((y + 1) * y / 2 <= t) ++y;
        int xs = t - y * (y - 1) / 2;
        size_t o0 = ((size_t)(xs * TB + (tid >> 4))) * N + y * TB + (tid & 15);
        out[o0] = 0.f;                         // z = 0
        out[o0 + (size_t)N * N] = 0.f;         // z = 1
    }

    __shared__ __align__(16) short sW2[512];        // [oc=16][k=32], k = khkw*8 + ic
    __shared__ __align__(16) short sW3[1024];       // [oc=16][k=64], k = khkw*16 + ic (oc>=8 zero)
    __shared__ __align__(16) short h1s[324 * 8];    // [pos 18x18][8ch] bf16, 16B/pos
    __shared__ __align__(16) short h2lo[289 * 8];   // [pos 17x17][ch 0-7]  bf16
    __shared__ __align__(16) short h2hi[289 * 8];   // [pos 17x17][ch 8-15] bf16
    __shared__ __align__(16) unsigned RM1[12];      // layer-1 mask, flat bitmap over 18x18
    __shared__ __align__(16) unsigned M2f[10];      // spread mask, flat bitmap over 17x17

    const int lane = tid & 63, wid = tid >> 6;
    const int c16 = lane & 15, g = lane >> 4;

    const float a1 = a1p[0], a2 = a2p[0], a3 = a3p[0];
    const float b4 = b4p[0];
    const bool leftEdge  = (tx0 == 0);
    const bool rightEdge = (tx0 == N - TB);

    // --- stage transposed bf16 weights ONCE (used by both batches) ---
    for (int u = tid; u < 512; u += 256) {
        int o = u >> 5, khkw = (u >> 3) & 3, i = u & 7;
        sW2[u] = f2bf(w2[((o * 8 + i) * 2 + (khkw >> 1)) * 2 + (khkw & 1)]);
    }
    for (int u = tid; u < 1024; u += 256) {
        int oc = u >> 6, k = u & 63, khkw = k >> 4, i = k & 15;
        sW3[u] = (oc < 8) ? f2bf(w3[((oc * 16 + i) * 2 + (khkw >> 1)) * 2 + (khkw & 1)]) : (short)0;
    }

    // position slots for Phase A (324 positions over 256 threads: 2 slots)
    const int pA0 = tid;                 // always < 324
    const int pA1 = tid + 256;           // valid iff tid < 68
    const bool s1valid = (pA1 < 324);
    const bool s1wave  = ((tid - lane) + 256 < 324);   // wave-uniform: waves 0,1 only

    const int dyA0 = pA0 / 18, dxA0 = pA0 - dyA0 * 18;
    const int dyA1 = pA1 / 18, dxA1 = pA1 - dyA1 * 18;

    // ================= Phase A (z=0) =================
    {
        // slot 0
        int gy = ty0 - 1 + dyA0, gx = tx0 - 1 + dxA0;
        bool mb = false; float xv = 0.f;
        if ((unsigned)gy < N && (unsigned)gx < N) {
            size_t idx = ((size_t)gy) * N + gx;
            mb = (maskg[idx] > 0); xv = xg[idx];
        }
        unsigned long long bal = __ballot(mb);
        if (lane == 0) *(uint2*)&RM1[2 * wid] = make_uint2((unsigned)bal, (unsigned)(bal >> 32));
        short8 hv;
#pragma unroll
        for (int ch = 0; ch < 8; ++ch) hv[ch] = f2bf(prelu(fmaf(xv, w1[ch], b1[ch]), a1));
        if (!mb) hv = (short8)0;
        *(short8*)&h1s[pA0 * 8] = hv;

        // slot 1
        if (s1wave) {
            bool mb1 = false; float xv1 = 0.f;
            if (s1valid) {
                int gy1 = ty0 - 1 + dyA1, gx1 = tx0 - 1 + dxA1;
                if ((unsigned)gy1 < N && (unsigned)gx1 < N) {
                    size_t idx = ((size_t)gy1) * N + gx1;
                    mb1 = (maskg[idx] > 0); xv1 = xg[idx];
                }
            }
            unsigned long long bal1 = __ballot(mb1);
            if (lane == 0) *(uint2*)&RM1[2 * (wid + 4)] = make_uint2((unsigned)bal1, (unsigned)(bal1 >> 32));
            if (s1valid) {
                short8 hv1;
#pragma unroll
                for (int ch = 0; ch < 8; ++ch) hv1[ch] = f2bf(prelu(fmaf(xv1, w1[ch], b1[ch]), a1));
                if (!mb1) hv1 = (short8)0;
                *(short8*)&h1s[pA1 * 8] = hv1;
            }
        }
    }
    __syncthreads();

    // fragments/bias (used by both batches)
    short8 a2f = *(const short8*)&sW2[c16 * 32 + g * 8];
    f32x4 bias2;
#pragma unroll
    for (int r = 0; r < 4; ++r) bias2[r] = b2[g * 4 + r];

    // ================= Phase B (z=0) =================
    {
        const int kh = g >> 1, kw = g & 1;
#pragma unroll
        for (int k = 0; k < 5; ++k) {
            if (k == 4 && wid == 3) break;            // wave-uniform
            const int grp = (k < 4) ? (wid + 4 * k) : (16 + wid);
            int p = grp * 16 + c16;
            bool valid = p < 289;
            int pc = valid ? p : 288;
            int dy2 = pc / 17, dx2 = pc - dy2 * 17;

            short8 bf = *(const short8*)&h1s[((dy2 + kh) * 18 + dx2 + kw) * 8];
            f32x4 acc = __builtin_amdgcn_mfma_f32_16x16x32_bf16(a2f, bf, bias2, 0, 0, 0);

            int q = dy2 * 18 + dx2, w0 = q >> 5, sh = q & 31;
            unsigned long long v64 = ((unsigned long long)RM1[w0 + 1] << 32) | RM1[w0];
            unsigned long long v = v64 >> sh;
            unsigned m2 = (unsigned)((v | (v >> 1) | (v >> 18) | (v >> 19)) & 1ull);
            if ((leftEdge && dx2 == 0) || (rightEdge && dx2 == 16)) m2 = 0;
            if (!valid) m2 = 0;

            unsigned long long balm = __ballot(m2 != 0);
            if (lane == 0) ((unsigned short*)M2f)[grp] = (unsigned short)(balm & 0xFFFFull);

            short4v hv;
#pragma unroll
            for (int r = 0; r < 4; ++r) hv[r] = f2bf(prelu(acc[r], a2));
            if (m2 == 0) { hv[0] = 0; hv[1] = 0; hv[2] = 0; hv[3] = 0; }

            if (valid) {
                short* dst = (g & 2) ? (short*)h2hi : (short*)h2lo;
                *(short4v*)&dst[pc * 8 + (g & 1) * 4] = hv;
            }
        }
    }
    __syncthreads();

    // ============ Phase A(z=1) load-issue (hides under C0) ============
    bool mbZ0 = false, mbZ1 = false;
    float xvZ0 = 0.f, xvZ1 = 0.f;
    {
        int gy = ty0 - 1 + dyA0, gx = tx0 - 1 + dxA0;
        if ((unsigned)gy < N && (unsigned)gx < N) {
            size_t idx = (size_t)N * N + (size_t)gy * N + gx;
            mbZ0 = (maskg[idx] > 0); xvZ0 = xg[idx];
        }
        if (s1valid) {
            int gy1 = ty0 - 1 + dyA1, gx1 = tx0 - 1 + dxA1;
            if ((unsigned)gy1 < N && (unsigned)gx1 < N) {
                size_t idx = (size_t)N * N + (size_t)gy1 * N + gx1;
                mbZ1 = (maskg[idx] > 0); xvZ1 = xg[idx];
            }
        }
    }

    // Phase C fragments (shared by both batches)
    short8 a3f0 = *(const short8*)&sW3[c16 * 64 + g * 8];        // k 0..31  (kh=0)
    short8 a3f1 = *(const short8*)&sW3[c16 * 64 + 32 + g * 8];   // k 32..63 (kh=1)
    const int kwC = g >> 1, ic8 = g & 1;
    const short* h2sel = ic8 ? (const short*)h2hi : (const short*)h2lo;
    const int base = wid * 4;
    f32x4 bias3;
    float w4r[4];
#pragma unroll
    for (int r = 0; r < 4; ++r) {
        bias3[r] = (g < 2) ? b3[g * 4 + r] : 0.f;
        w4r[r]   = (g < 2) ? w4[g * 4 + r] : 0.f;
    }

    // ================= Phase C (z=0) =================
    {
        short8 bfp = *(const short8*)&h2sel[(base * 17 + c16 + kwC) * 8];
#pragma unroll
        for (int j = 0; j < 4; ++j) {
            const int G = base + j;
            short8 bfn = *(const short8*)&h2sel[((G + 1) * 17 + c16 + kwC) * 8];
            f32x4 acc = __builtin_amdgcn_mfma_f32_16x16x32_bf16(a3f0, bfp, bias3, 0, 0, 0);
            acc = __builtin_amdgcn_mfma_f32_16x16x32_bf16(a3f1, bfn, acc, 0, 0, 0);
            bfp = bfn;

            float partial = 0.f;
#pragma unroll
            for (int r = 0; r < 4; ++r) partial = fmaf(prelu(acc[r], a3), w4r[r], partial);
            partial += __shfl_xor(partial, 16, 64);   // oc live only in g=0,1

            if (g == 0) {
                int q2 = G * 17 + c16, w2i = q2 >> 5, sh2 = q2 & 31;
                unsigned long long v64 = ((unsigned long long)M2f[w2i + 1] << 32) | M2f[w2i];
                unsigned long long v = v64 >> sh2;
                unsigned m3 = (unsigned)((v | (v >> 1) | (v >> 17) | (v >> 18)) & 1ull);

                float outv = m3 ? (partial + b4) : 0.f;
                int y = ty0 + G, x = tx0 + c16;
                if (y < x) {
                    outv = 0.f;
                } else if (y == x && m3) {
                    outv = fmaxf(outv, 0.f) + log1pf(expf(-fabsf(outv)));
                }
                out[((size_t)y) * N + x] = outv;
            }
        }
    }

    // ============ Phase A(z=1) finish: ballots + h1 into LDS ============
    {
        unsigned long long bal = __ballot(mbZ0);
        if (lane == 0) *(uint2*)&RM1[2 * wid] = make_uint2((unsigned)bal, (unsigned)(bal >> 32));
        short8 hv;
#pragma unroll
        for (int ch = 0; ch < 8; ++ch) hv[ch] = f2bf(prelu(fmaf(xvZ0, w1[ch], b1[ch]), a1));
        if (!mbZ0) hv = (short8)0;
        *(short8*)&h1s[pA0 * 8] = hv;

        if (s1wave) {
            unsigned long long bal1 = __ballot(mbZ1);
            if (lane == 0) *(uint2*)&RM1[2 * (wid + 4)] = make_uint2((unsigned)bal1, (unsigned)(bal1 >> 32));
            if (s1valid) {
                short8 hv1;
#pragma unroll
                for (int ch = 0; ch < 8; ++ch) hv1[ch] = f2bf(prelu(fmaf(xvZ1, w1[ch], b1[ch]), a1));
                if (!mbZ1) hv1 = (short8)0;
                *(short8*)&h1s[pA1 * 8] = hv1;
            }
        }
    }
    __syncthreads();

    // ================= Phase B (z=1) =================
    {
        const int kh = g >> 1, kw = g & 1;
#pragma unroll
        for (int k = 0; k < 5; ++k) {
            if (k == 4 && wid == 3) break;            // wave-uniform
            const int grp = (k < 4) ? (wid + 4 * k) : (16 + wid);
            int p = grp * 16 + c16;
            bool valid = p < 289;
            int pc = valid ? p : 288;
            int dy2 = pc / 17, dx2 = pc - dy2 * 17;

            short8 bf = *(const short8*)&h1s[((dy2 + kh) * 18 + dx2 + kw) * 8];
            f32x4 acc = __builtin_amdgcn_mfma_f32_16x16x32_bf16(a2f, bf, bias2, 0, 0, 0);

            int q = dy2 * 18 + dx2, w0 = q >> 5, sh = q & 31;
            unsigned long long v64 = ((unsigned long long)RM1[w0 + 1] << 32) | RM1[w0];
            unsigned long long v = v64 >> sh;
            unsigned m2 = (unsigned)((v | (v >> 1) | (v >> 18) | (v >> 19)) & 1ull);
            if ((leftEdge && dx2 == 0) || (rightEdge && dx2 == 16)) m2 = 0;
            if (!valid) m2 = 0;

            unsigned long long balm = __ballot(m2 != 0);
            if (lane == 0) ((unsigned short*)M2f)[grp] = (unsigned short)(balm & 0xFFFFull);

            short4v hv;
#pragma unroll
            for (int r = 0; r < 4; ++r) hv[r] = f2bf(prelu(acc[r], a2));
            if (m2 == 0) { hv[0] = 0; hv[1] = 0; hv[2] = 0; hv[3] = 0; }

            if (valid) {
                short* dst = (g & 2) ? (short*)h2hi : (short*)h2lo;
                *(short4v*)&dst[pc * 8 + (g & 1) * 4] = hv;
            }
        }
    }
    __syncthreads();

    // ================= Phase C (z=1) =================
    {
        short8 bfp = *(const short8*)&h2sel[(base * 17 + c16 + kwC) * 8];
#pragma unroll
        for (int j = 0; j < 4; ++j) {
            const int G = base + j;
            short8 bfn = *(const short8*)&h2sel[((G + 1) * 17 + c16 + kwC) * 8];
            f32x4 acc = __builtin_amdgcn_mfma_f32_16x16x32_bf16(a3f0, bfp, bias3, 0, 0, 0);
            acc = __builtin_amdgcn_mfma_f32_16x16x32_bf16(a3f1, bfn, acc, 0, 0, 0);
            bfp = bfn;

            float partial = 0.f;
#pragma unroll
            for (int r = 0; r < 4; ++r) partial = fmaf(prelu(acc[r], a3), w4r[r], partial);
            partial += __shfl_xor(partial, 16, 64);

            if (g == 0) {
                int q2 = G * 17 + c16, w2i = q2 >> 5, sh2 = q2 & 31;
                unsigned long long v64 = ((unsigned long long)M2f[w2i + 1] << 32) | M2f[w2i];
                unsigned long long v = v64 >> sh2;
                unsigned m3 = (unsigned)((v | (v >> 1) | (v >> 17) | (v >> 18)) & 1ull);

                float outv = m3 ? (partial + b4) : 0.f;
                int y = ty0 + G, x = tx0 + c16;
                if (y < x) {
                    outv = 0.f;
                } else if (y == x && m3) {
                    outv = fmaxf(outv, 0.f) + log1pf(expf(-fabsf(outv)));
                }
                out[(size_t)N * N + (size_t)y * N + x] = outv;
            }
        }
    }
}

extern "C" void kernel_launch(void* const* d_in, const int* in_sizes, int n_in,
                              void* d_out, int out_size, void* d_ws, size_t ws_size,
                              hipStream_t stream) {
    const float* x    = (const float*)d_in[0];
    const int*   mask = (const int*)  d_in[1];
    const float* w1   = (const float*)d_in[2];
    const float* b1   = (const float*)d_in[3];
    const float* a1   = (const float*)d_in[4];
    const float* w2   = (const float*)d_in[5];
    const float* b2   = (const float*)d_in[6];
    const float* a2   = (const float*)d_in[7];
    const float* w3   = (const float*)d_in[8];
    const float* b3   = (const float*)d_in[9];
    const float* a3   = (const float*)d_in[10];
    const float* w4   = (const float*)d_in[11];
    const float* b4   = (const float*)d_in[12];
    float* out = (float*)d_out;

    dim3 grid(2080, 1, 1);   // one block per lower-triangle tile, both batches
    precond_mfma<<<grid, 256, 0, stream>>>(x, mask, w1, b1, a1, w2, b2, a2,
                                           w3, b3, a3, w4, b4, out);
}

// Round 13
// 27.165 us; speedup vs baseline: 1.5126x; 1.5126x over previous
//
#include <hip/hip_runtime.h>
#include <hip/hip_bf16.h>
#include <math.h>

#define N 1024
#define TB 16

typedef __attribute__((ext_vector_type(8))) short short8;
typedef __attribute__((ext_vector_type(4))) short short4v;
typedef __attribute__((ext_vector_type(4))) float f32x4;

// PReLU via max/min: max(v,0) + a*min(v,0)
__device__ __forceinline__ float prelu(float v, float a) {
    return fmaxf(v, 0.f) + a * fminf(v, 0.f);
}

// f32 -> bf16 RNE via hardware cvt (pairs into v_cvt_pk_bf16_f32)
__device__ __forceinline__ short f2bf(float f) {
    return (short)__bfloat16_as_ushort(__float2bfloat16(f));
}

// R13: cooperative Phase A + ONE barrier; Phase B/C wave-private (no barriers).
// Wave w owns output rows 4w..4w+3 and computes h2 rows 4w..4w+4 (85 positions)
// into its private LDS region; its m2 mask lives in a 96-bit register bitmap.
__global__ __launch_bounds__(256, 8) void precond_mfma(
    const float* __restrict__ xg, const int* __restrict__ maskg,
    const float* __restrict__ w1, const float* __restrict__ b1, const float* __restrict__ a1p,
    const float* __restrict__ w2, const float* __restrict__ b2, const float* __restrict__ a2p,
    const float* __restrict__ w3, const float* __restrict__ b3, const float* __restrict__ a3p,
    const float* __restrict__ w4, const float* __restrict__ b4p,
    float* __restrict__ out)
{
    const int tid = threadIdx.x;
    const int bz  = blockIdx.z;
    const int t   = blockIdx.x;

    // ---- triangular mapping: t -> (by, bx), bx <= by ----
    int by = (int)((sqrtf(8.0f * (float)t + 1.0f) - 1.0f) * 0.5f);
    while ((by + 1) * (by + 2) / 2 <= t) ++by;
    while (by * (by + 1) / 2 > t) --by;
    const int bx = t - by * (by + 1) / 2;
    const int ty0 = by * TB, tx0 = bx * TB;

    // ---- fused zero-fill: block t (t<2016) clears upper tile #t ----
    if (t < 2016) {
        int y = (int)((sqrtf(8.0f * (float)t + 1.0f) + 1.0f) * 0.5f);
        while (y * (y - 1) / 2 > t) --y;
        while ((y + 1) * y / 2 <= t) ++y;
        int xs = t - y * (y - 1) / 2;
        int zy = xs * TB + (tid >> 4), zx = y * TB + (tid & 15);
        out[((size_t)bz * N + zy) * N + zx] = 0.f;   // fire-and-forget
    }

    __shared__ __align__(16) short sW2[512];        // [oc=16][k=32], k = khkw*8 + ic
    __shared__ __align__(16) short sW3[1024];       // [oc=16][k=64], k = khkw*16 + ic (oc>=8 zero)
    __shared__ __align__(16) short h1s[324 * 8];    // [pos 18x18][8ch] bf16, 16B/pos
    __shared__ __align__(16) short h2lo[4][85 * 8]; // per-wave: [pos 5x17][ch 0-7]
    __shared__ __align__(16) short h2hi[4][85 * 8]; // per-wave: [pos 5x17][ch 8-15]
    __shared__ __align__(16) unsigned RM1[12];      // layer-1 mask, flat bitmap over 18x18

    const int lane = tid & 63, wid = tid >> 6;
    const int c16 = lane & 15, g = lane >> 4;

    const float a1 = a1p[0], a2 = a2p[0], a3 = a3p[0];
    const float b4 = b4p[0];
    const bool leftEdge  = (tx0 == 0);
    const bool rightEdge = (tx0 == N - TB);

    // --- stage transposed bf16 weights (coalesced, LDS) ---
    for (int u = tid; u < 512; u += 256) {
        int o = u >> 5, khkw = (u >> 3) & 3, i = u & 7;
        sW2[u] = f2bf(w2[((o * 8 + i) * 2 + (khkw >> 1)) * 2 + (khkw & 1)]);
    }
    for (int u = tid; u < 1024; u += 256) {
        int oc = u >> 6, k = u & 63, khkw = k >> 4, i = k & 15;
        sW3[u] = (oc < 8) ? f2bf(w3[((oc * 16 + i) * 2 + (khkw >> 1)) * 2 + (khkw & 1)]) : (short)0;
    }

    // --- Phase A: h1 (masked, PReLU'd, bf16) + ballot mask bitmap (18x18 halo) ---
    for (int p = tid; p < 324; p += 256) {
        int dy = p / 18, dx = p - dy * 18;
        int gy = ty0 - 1 + dy, gx = tx0 - 1 + dx;
        bool mb = false;
        float xv = 0.f;
        if ((unsigned)gy < N && (unsigned)gx < N) {
            size_t idx = ((size_t)bz * N + gy) * N + gx;
            mb = (maskg[idx] > 0);
            xv = xg[idx];
        }
        unsigned long long bal = __ballot(mb);
        if (lane == 0) {
            int c = (p - lane) >> 6;    // chunk index
            *(uint2*)&RM1[2 * c] = make_uint2((unsigned)bal, (unsigned)(bal >> 32));
        }
        short8 hv;
#pragma unroll
        for (int ch = 0; ch < 8; ++ch) hv[ch] = f2bf(prelu(fmaf(xv, w1[ch], b1[ch]), a1));
        if (!mb) hv = (short8)0;
        *(short8*)&h1s[p * 8] = hv;
    }
    __syncthreads();   // the ONLY barrier

    // --- Phase B (wave-private): h2 rows 4w..4w+4 (85 pos, 6 groups) via MFMA ---
    unsigned M2w0, M2w1, M2w2;    // 96-bit m2 bitmap (local positions 0..84)
    {
        short8 a2f = *(const short8*)&sW2[c16 * 32 + g * 8];
        const int kh = g >> 1, kw = g & 1;
        const int rowbase = wid * 4;
        f32x4 bias2;
#pragma unroll
        for (int r = 0; r < 4; ++r) bias2[r] = b2[g * 4 + r];

        unsigned mw[3] = {0, 0, 0};
#pragma unroll
        for (int grp = 0; grp < 6; ++grp) {
            int pl = grp * 16 + c16;              // local position 0..95
            bool valid = pl < 85;
            int plc = valid ? pl : 84;
            int lr = plc / 17, dx2 = plc - lr * 17;
            int dy2 = rowbase + lr;               // global h2 row

            short8 bf = *(const short8*)&h1s[((dy2 + kh) * 18 + dx2 + kw) * 8];
            f32x4 acc = __builtin_amdgcn_mfma_f32_16x16x32_bf16(a2f, bf, bias2, 0, 0, 0);

            // spread mask from flat bitmap: bits q, q+1, q+18, q+19 of RM1
            int q = dy2 * 18 + dx2, w0 = q >> 5, sh = q & 31;
            unsigned long long v64 = ((unsigned long long)RM1[w0 + 1] << 32) | RM1[w0];
            unsigned long long v = v64 >> sh;
            unsigned m2 = (unsigned)((v | (v >> 1) | (v >> 18) | (v >> 19)) & 1ull);
            if ((leftEdge && dx2 == 0) || (rightEdge && dx2 == 16)) m2 = 0;
            if (!valid) m2 = 0;

            // accumulate register m2 bitmap (bits 0-15 of ballot = g=0 lanes)
            unsigned bits16 = (unsigned)(__ballot(m2 != 0) & 0xFFFFull);
            if (grp == 0) mw[0]  = bits16;
            if (grp == 1) mw[0] |= bits16 << 16;
            if (grp == 2) mw[1]  = bits16;
            if (grp == 3) mw[1] |= bits16 << 16;
            if (grp == 4) mw[2]  = bits16;
            if (grp == 5) mw[2] |= bits16 << 16;

            short4v hv;
#pragma unroll
            for (int r = 0; r < 4; ++r) hv[r] = f2bf(prelu(acc[r], a2));
            if (m2 == 0) { hv[0] = 0; hv[1] = 0; hv[2] = 0; hv[3] = 0; }

            if (valid) {
                short* dst = (g & 2) ? &h2hi[wid][0] : &h2lo[wid][0];
                *(short4v*)&dst[plc * 8 + (g & 1) * 4] = hv;
            }
        }
        M2w0 = mw[0]; M2w1 = mw[1]; M2w2 = mw[2];
    }
    // no barrier: wave consumes only its own h2 region (lgkmcnt-ordered)

    // --- Phase C (wave-private): 4 output rows; 2 chained MFMAs (K=64) + epilogue ---
    {
        short8 a3f0 = *(const short8*)&sW3[c16 * 64 + g * 8];        // k 0..31  (kh=0)
        short8 a3f1 = *(const short8*)&sW3[c16 * 64 + 32 + g * 8];   // k 32..63 (kh=1)
        const int kwC = g >> 1, ic8 = g & 1;
        const short* h2sel = ic8 ? &h2hi[wid][0] : &h2lo[wid][0];
        f32x4 bias3;
        float w4r[4];
#pragma unroll
        for (int r = 0; r < 4; ++r) {
            bias3[r] = (g < 2) ? b3[g * 4 + r] : 0.f;
            w4r[r]   = (g < 2) ? w4[g * 4 + r] : 0.f;
        }

        // 17-bit row masks of the 96-bit bitmap, compile-time word/shift per row
        unsigned rm[5];
        rm[0] = M2w0 & 0x1FFFFu;
        rm[1] = (unsigned)((((unsigned long long)M2w1 << 32) | M2w0) >> 17) & 0x1FFFFu;
        rm[2] = (M2w1 >> 2) & 0x1FFFFu;
        rm[3] = (unsigned)((((unsigned long long)M2w2 << 32) | M2w1) >> 19) & 0x1FFFFu;
        rm[4] = (M2w2 >> 4) & 0x1FFFFu;

        // row-fragment reuse: local rows 0..4 read once each
        short8 bfp = *(const short8*)&h2sel[(c16 + kwC) * 8];
#pragma unroll
        for (int j = 0; j < 4; ++j) {
            short8 bfn = *(const short8*)&h2sel[((j + 1) * 17 + c16 + kwC) * 8];
            f32x4 acc = __builtin_amdgcn_mfma_f32_16x16x32_bf16(a3f0, bfp, bias3, 0, 0, 0);
            acc = __builtin_amdgcn_mfma_f32_16x16x32_bf16(a3f1, bfn, acc, 0, 0, 0);
            bfp = bfn;

            float partial = 0.f;
#pragma unroll
            for (int r = 0; r < 4; ++r) partial = fmaf(prelu(acc[r], a3), w4r[r], partial);
            partial += __shfl_xor(partial, 16, 64);   // oc live only in g=0,1

            if (g == 0) {
                unsigned combined = rm[j] | rm[j + 1];
                unsigned m3 = (combined >> c16) & 3u;

                float outv = m3 ? (partial + b4) : 0.f;
                int y = ty0 + wid * 4 + j, x = tx0 + c16;
                if (y < x) {
                    outv = 0.f;
                } else if (y == x && m3) {
                    outv = fmaxf(outv, 0.f) + log1pf(expf(-fabsf(outv)));
                }
                out[((size_t)bz * N + y) * N + x] = outv;
            }
        }
    }
}

extern "C" void kernel_launch(void* const* d_in, const int* in_sizes, int n_in,
                              void* d_out, int out_size, void* d_ws, size_t ws_size,
                              hipStream_t stream) {
    const float* x    = (const float*)d_in[0];
    const int*   mask = (const int*)  d_in[1];
    const float* w1   = (const float*)d_in[2];
    const float* b1   = (const float*)d_in[3];
    const float* a1   = (const float*)d_in[4];
    const float* w2   = (const float*)d_in[5];
    const float* b2   = (const float*)d_in[6];
    const float* a2   = (const float*)d_in[7];
    const float* w3   = (const float*)d_in[8];
    const float* b3   = (const float*)d_in[9];
    const float* a3   = (const float*)d_in[10];
    const float* w4   = (const float*)d_in[11];
    const float* b4   = (const float*)d_in[12];
    float* out = (float*)d_out;

    dim3 grid(2080, 1, 2);   // lower-triangle tiles only; zero tiles fused
    precond_mfma<<<grid, 256, 0, stream>>>(x, mask, w1, b1, a1, w2, b2, a2,
                                           w3, b3, a3, w4, b4, out);
}

// Round 14
// 25.581 us; speedup vs baseline: 1.6063x; 1.0619x over previous
//
#include <hip/hip_runtime.h>
#include <hip/hip_bf16.h>
#include <math.h>

#define N 1024
#define TB 16

typedef __attribute__((ext_vector_type(8))) short short8;
typedef __attribute__((ext_vector_type(4))) short short4v;
typedef __attribute__((ext_vector_type(4))) float f32x4;

// PReLU via max/min: max(v,0) + a*min(v,0)
__device__ __forceinline__ float prelu(float v, float a) {
    return fmaxf(v, 0.f) + a * fminf(v, 0.f);
}

// f32 -> bf16 RNE via hardware cvt (pairs into v_cvt_pk_bf16_f32)
__device__ __forceinline__ short f2bf(float f) {
    return (short)__bfloat16_as_ushort(__float2bfloat16(f));
}

// R14: R13 structure (coop Phase A + 1 barrier + wave-private B/C) with all
// global loads batch-issued at kernel top so their latency overlaps the
// prologue, closed-form zero-tile mapping, and halved sW3.
__global__ __launch_bounds__(256, 8) void precond_mfma(
    const float* __restrict__ xg, const int* __restrict__ maskg,
    const float* __restrict__ w1, const float* __restrict__ b1, const float* __restrict__ a1p,
    const float* __restrict__ w2, const float* __restrict__ b2, const float* __restrict__ a2p,
    const float* __restrict__ w3, const float* __restrict__ b3, const float* __restrict__ a3p,
    const float* __restrict__ w4, const float* __restrict__ b4p,
    float* __restrict__ out)
{
    const int tid = threadIdx.x;
    const int bz  = blockIdx.z;
    const int t   = blockIdx.x;

    // ---- triangular mapping: t -> (by, bx), bx <= by ----
    int by = (int)((sqrtf(8.0f * (float)t + 1.0f) - 1.0f) * 0.5f);
    while ((by + 1) * (by + 2) / 2 <= t) ++by;
    while (by * (by + 1) / 2 > t) --by;
    const int bx = t - by * (by + 1) / 2;
    const int ty0 = by * TB, tx0 = bx * TB;

    const int lane = tid & 63, wid = tid >> 6;
    const int c16 = lane & 15, g = lane >> 4;

    // ================= EARLY GLOBAL LOADS (all issued up front) =================
    // weights (coalesced by source index; scattered to LDS later)
    const float w2r0 = w2[tid];
    const float w2r1 = w2[tid + 256];
    const float w3r0 = w3[tid];          // w3 has 512 elements (8 oc)
    const float w3r1 = w3[tid + 256];

    // Phase A positions (324 over 256 threads: 2 slots)
    const int pA0 = tid;
    const int pA1 = tid + 256;
    const bool s1valid = (pA1 < 324);
    const bool s1wave  = ((tid - lane) + 256 < 324);   // wave-uniform: waves 0,1
    const int dyA0 = pA0 / 18, dxA0 = pA0 - dyA0 * 18;
    const int dyA1 = pA1 / 18, dxA1 = pA1 - dyA1 * 18;

    int gy0 = ty0 - 1 + dyA0, gx0 = tx0 - 1 + dxA0;
    const bool in0 = (unsigned)gy0 < N && (unsigned)gx0 < N;
    size_t i0 = in0 ? (((size_t)bz * N + gy0) * N + gx0) : 0;
    const int   mr0 = maskg[i0];         // unconditional load, clamped addr
    const float xr0 = xg[i0];

    int mr1 = 0; float xr1 = 0.f; bool in1 = false;
    if (s1wave) {
        int gy1 = ty0 - 1 + dyA1, gx1 = tx0 - 1 + dxA1;
        in1 = s1valid && (unsigned)gy1 < N && (unsigned)gx1 < N;
        size_t i1 = in1 ? (((size_t)bz * N + gy1) * N + gx1) : 0;
        mr1 = maskg[i1];
        xr1 = xg[i1];
    }

    // ---- fused zero-fill (closed form): upper tile = (row=bx, col=by+1) ----
    // runs while the loads above are in flight
    if (by < 63) {
        int zy = bx * TB + (tid >> 4), zx = (by + 1) * TB + (tid & 15);
        out[((size_t)bz * N + zy) * N + zx] = 0.f;   // fire-and-forget
    }

    __shared__ __align__(16) short sW2[512];        // [oc=16][k=32], k = khkw*8 + ic
    __shared__ __align__(16) short sW3h[512];       // [oc=8][k=64],  k = khkw*16 + ic
    __shared__ __align__(16) short h1s[324 * 8];    // [pos 18x18][8ch] bf16, 16B/pos
    __shared__ __align__(16) short h2lo[4][85 * 8]; // per-wave: [pos 5x17][ch 0-7]
    __shared__ __align__(16) short h2hi[4][85 * 8]; // per-wave: [pos 5x17][ch 8-15]
    __shared__ __align__(16) unsigned RM1[12];      // layer-1 mask, flat bitmap over 18x18

    const float a1 = a1p[0], a2 = a2p[0], a3 = a3p[0];
    const float b4 = b4p[0];
    const bool leftEdge  = (tx0 == 0);
    const bool rightEdge = (tx0 == N - TB);

    // ---- scatter weights into LDS (consume early loads) ----
    // w2 src s = o*32 + i*4 + khkw  ->  dst = o*32 + khkw*8 + i
    {
        int s0 = tid, s1 = tid + 256;
        sW2[(s0 & ~31) | ((s0 & 3) << 3) | ((s0 >> 2) & 7)] = f2bf(w2r0);
        sW2[(s1 & ~31) | ((s1 & 3) << 3) | ((s1 >> 2) & 7)] = f2bf(w2r1);
        // w3 src s = oc*64 + i*4 + khkw  ->  dst = oc*64 + khkw*16 + i
        sW3h[(s0 & ~63) | ((s0 & 3) << 4) | ((s0 >> 2) & 15)] = f2bf(w3r0);
        sW3h[(s1 & ~63) | ((s1 & 3) << 4) | ((s1 >> 2) & 15)] = f2bf(w3r1);
    }

    // ---- Phase A: h1 + ballot mask bitmap (consume early loads) ----
    {
        bool mb = in0 && (mr0 > 0);
        float xv = in0 ? xr0 : 0.f;
        unsigned long long bal = __ballot(mb);
        if (lane == 0) *(uint2*)&RM1[2 * wid] = make_uint2((unsigned)bal, (unsigned)(bal >> 32));
        short8 hv;
#pragma unroll
        for (int ch = 0; ch < 8; ++ch) hv[ch] = f2bf(prelu(fmaf(xv, w1[ch], b1[ch]), a1));
        if (!mb) hv = (short8)0;
        *(short8*)&h1s[pA0 * 8] = hv;

        if (s1wave) {
            bool mb1 = in1 && (mr1 > 0);
            float xv1 = in1 ? xr1 : 0.f;
            unsigned long long bal1 = __ballot(mb1);
            if (lane == 0) *(uint2*)&RM1[2 * (wid + 4)] = make_uint2((unsigned)bal1, (unsigned)(bal1 >> 32));
            if (s1valid) {
                short8 hv1;
#pragma unroll
                for (int ch = 0; ch < 8; ++ch) hv1[ch] = f2bf(prelu(fmaf(xv1, w1[ch], b1[ch]), a1));
                if (!mb1) hv1 = (short8)0;
                *(short8*)&h1s[pA1 * 8] = hv1;
            }
        }
    }
    __syncthreads();   // the ONLY barrier

    // --- Phase B (wave-private): h2 rows 4w..4w+4 (85 pos, 6 groups) via MFMA ---
    unsigned M2w0, M2w1, M2w2;    // 96-bit m2 bitmap (local positions 0..84)
    {
        short8 a2f = *(const short8*)&sW2[c16 * 32 + g * 8];
        const int kh = g >> 1, kw = g & 1;
        const int rowbase = wid * 4;
        f32x4 bias2;
#pragma unroll
        for (int r = 0; r < 4; ++r) bias2[r] = b2[g * 4 + r];

        unsigned mw[3] = {0, 0, 0};
#pragma unroll
        for (int grp = 0; grp < 6; ++grp) {
            int pl = grp * 16 + c16;              // local position 0..95
            bool valid = pl < 85;
            int plc = valid ? pl : 84;
            int lr = plc / 17, dx2 = plc - lr * 17;
            int dy2 = rowbase + lr;               // global h2 row

            short8 bf = *(const short8*)&h1s[((dy2 + kh) * 18 + dx2 + kw) * 8];
            f32x4 acc = __builtin_amdgcn_mfma_f32_16x16x32_bf16(a2f, bf, bias2, 0, 0, 0);

            // spread mask from flat bitmap: bits q, q+1, q+18, q+19 of RM1
            int q = dy2 * 18 + dx2, w0 = q >> 5, sh = q & 31;
            unsigned long long v64 = ((unsigned long long)RM1[w0 + 1] << 32) | RM1[w0];
            unsigned long long v = v64 >> sh;
            unsigned m2 = (unsigned)((v | (v >> 1) | (v >> 18) | (v >> 19)) & 1ull);
            if ((leftEdge && dx2 == 0) || (rightEdge && dx2 == 16)) m2 = 0;
            if (!valid) m2 = 0;

            // accumulate register m2 bitmap (bits 0-15 of ballot = g=0 lanes)
            unsigned bits16 = (unsigned)(__ballot(m2 != 0) & 0xFFFFull);
            if (grp == 0) mw[0]  = bits16;
            if (grp == 1) mw[0] |= bits16 << 16;
            if (grp == 2) mw[1]  = bits16;
            if (grp == 3) mw[1] |= bits16 << 16;
            if (grp == 4) mw[2]  = bits16;
            if (grp == 5) mw[2] |= bits16 << 16;

            short4v hv;
#pragma unroll
            for (int r = 0; r < 4; ++r) hv[r] = f2bf(prelu(acc[r], a2));
            if (m2 == 0) { hv[0] = 0; hv[1] = 0; hv[2] = 0; hv[3] = 0; }

            if (valid) {
                short* dst = (g & 2) ? &h2hi[wid][0] : &h2lo[wid][0];
                *(short4v*)&dst[plc * 8 + (g & 1) * 4] = hv;
            }
        }
        M2w0 = mw[0]; M2w1 = mw[1]; M2w2 = mw[2];
    }
    // no barrier: wave consumes only its own h2 region (lgkmcnt-ordered)

    // --- Phase C (wave-private): 4 output rows; 2 chained MFMAs (K=64) + epilogue ---
    {
        short8 a3f0 = *(const short8*)&sW3h[(c16 & 7) * 64 + g * 8];        // k 0..31
        short8 a3f1 = *(const short8*)&sW3h[(c16 & 7) * 64 + 32 + g * 8];   // k 32..63
        if (c16 >= 8) { a3f0 = (short8)0; a3f1 = (short8)0; }               // oc>=8 rows are zero
        const int kwC = g >> 1, ic8 = g & 1;
        const short* h2sel = ic8 ? &h2hi[wid][0] : &h2lo[wid][0];
        f32x4 bias3;
        float w4r[4];
#pragma unroll
        for (int r = 0; r < 4; ++r) {
            bias3[r] = (g < 2) ? b3[g * 4 + r] : 0.f;
            w4r[r]   = (g < 2) ? w4[g * 4 + r] : 0.f;
        }

        // 17-bit row masks of the 96-bit bitmap
        unsigned rm[5];
        rm[0] = M2w0 & 0x1FFFFu;
        rm[1] = (unsigned)((((unsigned long long)M2w1 << 32) | M2w0) >> 17) & 0x1FFFFu;
        rm[2] = (M2w1 >> 2) & 0x1FFFFu;
        rm[3] = (unsigned)((((unsigned long long)M2w2 << 32) | M2w1) >> 19) & 0x1FFFFu;
        rm[4] = (M2w2 >> 4) & 0x1FFFFu;

        // row-fragment reuse: local rows 0..4 read once each
        short8 bfp = *(const short8*)&h2sel[(c16 + kwC) * 8];
#pragma unroll
        for (int j = 0; j < 4; ++j) {
            short8 bfn = *(const short8*)&h2sel[((j + 1) * 17 + c16 + kwC) * 8];
            f32x4 acc = __builtin_amdgcn_mfma_f32_16x16x32_bf16(a3f0, bfp, bias3, 0, 0, 0);
            acc = __builtin_amdgcn_mfma_f32_16x16x32_bf16(a3f1, bfn, acc, 0, 0, 0);
            bfp = bfn;

            float partial = 0.f;
#pragma unroll
            for (int r = 0; r < 4; ++r) partial = fmaf(prelu(acc[r], a3), w4r[r], partial);
            partial += __shfl_xor(partial, 16, 64);   // oc live only in g=0,1

            if (g == 0) {
                unsigned combined = rm[j] | rm[j + 1];
                unsigned m3 = (combined >> c16) & 3u;

                float outv = m3 ? (partial + b4) : 0.f;
                int y = ty0 + wid * 4 + j, x = tx0 + c16;
                if (y < x) {
                    outv = 0.f;
                } else if (y == x && m3) {
                    outv = fmaxf(outv, 0.f) + log1pf(expf(-fabsf(outv)));
                }
                out[((size_t)bz * N + y) * N + x] = outv;
            }
        }
    }
}

extern "C" void kernel_launch(void* const* d_in, const int* in_sizes, int n_in,
                              void* d_out, int out_size, void* d_ws, size_t ws_size,
                              hipStream_t stream) {
    const float* x    = (const float*)d_in[0];
    const int*   mask = (const int*)  d_in[1];
    const float* w1   = (const float*)d_in[2];
    const float* b1   = (const float*)d_in[3];
    const float* a1   = (const float*)d_in[4];
    const float* w2   = (const float*)d_in[5];
    const float* b2   = (const float*)d_in[6];
    const float* a2   = (const float*)d_in[7];
    const float* w3   = (const float*)d_in[8];
    const float* b3   = (const float*)d_in[9];
    const float* a3   = (const float*)d_in[10];
    const float* w4   = (const float*)d_in[11];
    const float* b4   = (const float*)d_in[12];
    float* out = (float*)d_out;

    dim3 grid(2080, 1, 2);   // lower-triangle tiles only; zero tiles fused
    precond_mfma<<<grid, 256, 0, stream>>>(x, mask, w1, b1, a1, w2, b2, a2,
                                           w3, b3, a3, w4, b4, out);
}

// Round 15
// 25.368 us; speedup vs baseline: 1.6198x; 1.0084x over previous
//
#include <hip/hip_runtime.h>
#include <hip/hip_bf16.h>
#include <math.h>

#define N 1024
#define TB 16

typedef __attribute__((ext_vector_type(8))) short short8;
typedef __attribute__((ext_vector_type(4))) short short4v;
typedef __attribute__((ext_vector_type(4))) float f32x4;

// PReLU via max/min: max(v,0) + a*min(v,0)
__device__ __forceinline__ float prelu(float v, float a) {
    return fmaxf(v, 0.f) + a * fminf(v, 0.f);
}

// f32 -> bf16 RNE via hardware cvt (pairs into v_cvt_pk_bf16_f32)
__device__ __forceinline__ short f2bf(float f) {
    return (short)__bfloat16_as_ushort(__float2bfloat16(f));
}

// R15: two lower-triangle tiles per 512-thread block, processed in PARALLEL by
// independent 4-wave halves (not serialized like R12). Per-half structure is
// R14's: batched early loads, coop Phase A, ONE barrier, wave-private B/C.
// Masks flow through register bitmaps (m2row[5]) built bit-parallel per wave.
__global__ __launch_bounds__(512, 8) void precond_mfma(
    const float* __restrict__ xg, const int* __restrict__ maskg,
    const float* __restrict__ w1, const float* __restrict__ b1, const float* __restrict__ a1p,
    const float* __restrict__ w2, const float* __restrict__ b2, const float* __restrict__ a2p,
    const float* __restrict__ w3, const float* __restrict__ b3, const float* __restrict__ a3p,
    const float* __restrict__ w4, const float* __restrict__ b4p,
    float* __restrict__ out)
{
    const int tid  = threadIdx.x;
    const int bz   = blockIdx.z;
    const int h    = tid >> 8;            // half index: which tile this thread works
    const int tl   = tid & 255;           // thread id within half
    const int lane = tid & 63;
    const int widh = (tid >> 6) & 3;      // wave id within half
    const int c16  = lane & 15, g = lane >> 4;

    const int t = 2 * blockIdx.x + h;     // tile index 0..2079

    // ---- triangular mapping: t -> (by, bx), bx <= by ----
    int by = (int)((sqrtf(8.0f * (float)t + 1.0f) - 1.0f) * 0.5f);
    while ((by + 1) * (by + 2) / 2 <= t) ++by;
    while (by * (by + 1) / 2 > t) --by;
    const int bx = t - by * (by + 1) / 2;
    const int ty0 = by * TB, tx0 = bx * TB;

    // ================= EARLY GLOBAL LOADS (issued up front) =================
    const float w2r = w2[tid];            // 512 elements, 1/thread
    const float w3r = w3[tid];            // 512 elements, 1/thread

    // Phase A positions (324 per half over 256 threads: 2 slots)
    const int pA0 = tl;
    const int pA1 = tl + 256;
    const bool s1valid = (pA1 < 324);
    const bool s1wave  = (widh < 2);      // waves 0,1 of each half touch slot 1
    const int dyA0 = pA0 / 18, dxA0 = pA0 - dyA0 * 18;
    const int dyA1 = pA1 / 18, dxA1 = pA1 - dyA1 * 18;

    int gy0 = ty0 - 1 + dyA0, gx0 = tx0 - 1 + dxA0;
    const bool in0 = (unsigned)gy0 < N && (unsigned)gx0 < N;
    size_t i0 = in0 ? (((size_t)bz * N + gy0) * N + gx0) : 0;
    const int   mr0 = maskg[i0];          // unconditional load, clamped addr
    const float xr0 = xg[i0];

    int mr1 = 0; float xr1 = 0.f; bool in1 = false;
    if (s1wave) {
        int gy1 = ty0 - 1 + dyA1, gx1 = tx0 - 1 + dxA1;
        in1 = s1valid && (unsigned)gy1 < N && (unsigned)gx1 < N;
        size_t i1 = in1 ? (((size_t)bz * N + gy1) * N + gx1) : 0;
        mr1 = maskg[i1];
        xr1 = xg[i1];
    }

    // ---- fused zero-fill (closed form): upper tile = (row=bx, col=by+1) ----
    if (by < 63) {
        int zy = bx * TB + (tl >> 4), zx = (by + 1) * TB + (tl & 15);
        out[((size_t)bz * N + zy) * N + zx] = 0.f;   // fire-and-forget
    }

    __shared__ __align__(16) short sW2[512];          // [oc=16][k=32] (shared by halves)
    __shared__ __align__(16) short sW3h[512];         // [oc=8][k=64]  (shared by halves)
    __shared__ __align__(16) short h1s[2][324 * 8];   // per half: [pos 18x18][8ch]
    __shared__ __align__(16) short h2lo[2][4][85 * 8];// per half, per wave: ch 0-7
    __shared__ __align__(16) short h2hi[2][4][85 * 8];// per half, per wave: ch 8-15
    __shared__ unsigned RM1[2][12];                   // per half: 324-bit mask bitmap

    const float a1 = a1p[0], a2 = a2p[0], a3 = a3p[0];
    const float b4 = b4p[0];
    const bool leftEdge  = (tx0 == 0);
    const bool rightEdge = (tx0 == N - TB);

    // ---- scatter weights into LDS (consume early loads; 1 elem each) ----
    // w2 src s = o*32 + i*4 + khkw  ->  dst = o*32 + khkw*8 + i
    sW2[(tid & ~31) | ((tid & 3) << 3) | ((tid >> 2) & 7)] = f2bf(w2r);
    // w3 src s = oc*64 + i*4 + khkw ->  dst = oc*64 + khkw*16 + i
    sW3h[(tid & ~63) | ((tid & 3) << 4) | ((tid >> 2) & 15)] = f2bf(w3r);

    // ---- Phase A: h1 + ballot mask bitmap (consume early loads) ----
    {
        bool mb = in0 && (mr0 > 0);
        float xv = in0 ? xr0 : 0.f;
        unsigned long long bal = __ballot(mb);
        if (lane == 0) *(uint2*)&RM1[h][2 * widh] =
            make_uint2((unsigned)bal, (unsigned)(bal >> 32));
        short8 hv;
#pragma unroll
        for (int ch = 0; ch < 8; ++ch) hv[ch] = f2bf(prelu(fmaf(xv, w1[ch], b1[ch]), a1));
        if (!mb) hv = (short8)0;
        *(short8*)&h1s[h][pA0 * 8] = hv;

        if (s1wave) {
            bool mb1 = in1 && (mr1 > 0);
            float xv1 = in1 ? xr1 : 0.f;
            unsigned long long bal1 = __ballot(mb1);
            if (lane == 0) *(uint2*)&RM1[h][2 * (widh + 4)] =
                make_uint2((unsigned)bal1, (unsigned)(bal1 >> 32));
            if (s1valid) {
                short8 hv1;
#pragma unroll
                for (int ch = 0; ch < 8; ++ch) hv1[ch] = f2bf(prelu(fmaf(xv1, w1[ch], b1[ch]), a1));
                if (!mb1) hv1 = (short8)0;
                *(short8*)&h1s[h][pA1 * 8] = hv1;
            }
        }
    }
    __syncthreads();   // the ONLY barrier

    // ---- per-wave bit-parallel spread masks: m2row[5] (17 bits each) ----
    unsigned m2row[5];
    {
        const int bitbase = 72 * widh;    // 18 * (4*widh)
        unsigned rr[6];
#pragma unroll
        for (int i = 0; i < 6; ++i) {
            int bit = bitbase + 18 * i;
            int w = bit >> 5, sh = bit & 31;
            unsigned long long v = ((unsigned long long)RM1[h][w + 1] << 32) | RM1[h][w];
            rr[i] = (unsigned)(v >> sh);
        }
#pragma unroll
        for (int i = 0; i < 5; ++i) {
            unsigned u = rr[i] | rr[i + 1];
            m2row[i] = (u | (u >> 1)) & 0x1FFFFu;
        }
        if (leftEdge) {
#pragma unroll
            for (int i = 0; i < 5; ++i) m2row[i] &= ~1u;
        }
        if (rightEdge) {
#pragma unroll
            for (int i = 0; i < 5; ++i) m2row[i] &= ~(1u << 16);
        }
    }
    // 96-bit flat bitmap over local positions pl = lr*17+dx2
    unsigned M2w0 = m2row[0] | (m2row[1] << 17);
    unsigned M2w1 = (m2row[1] >> 15) | (m2row[2] << 2) | (m2row[3] << 19);
    unsigned M2w2 = (m2row[3] >> 13) | (m2row[4] << 4);

    // --- Phase B (wave-private): h2 rows 4w..4w+4 (85 pos, 6 groups) via MFMA ---
    {
        short8 a2f = *(const short8*)&sW2[c16 * 32 + g * 8];
        const int kh = g >> 1, kw = g & 1;
        const int rowbase = widh * 4;
        f32x4 bias2;
#pragma unroll
        for (int r = 0; r < 4; ++r) bias2[r] = b2[g * 4 + r];

#pragma unroll
        for (int grp = 0; grp < 6; ++grp) {
            int pl = grp * 16 + c16;              // local position 0..95
            bool valid = pl < 85;
            int plc = valid ? pl : 84;
            int lr = plc / 17, dx2 = plc - lr * 17;
            int dy2 = rowbase + lr;               // h2 row within tile

            short8 bf = *(const short8*)&h1s[h][((dy2 + kh) * 18 + dx2 + kw) * 8];
            f32x4 acc = __builtin_amdgcn_mfma_f32_16x16x32_bf16(a2f, bf, bias2, 0, 0, 0);

            // m2 bit: compile-time word select, 2 ops
            unsigned word = (grp < 2) ? M2w0 : ((grp < 4) ? M2w1 : M2w2);
            unsigned m2 = (word >> (c16 + ((grp & 1) << 4))) & 1u;

            short4v hv;
#pragma unroll
            for (int r = 0; r < 4; ++r) hv[r] = f2bf(prelu(acc[r], a2));
            if (m2 == 0) { hv[0] = 0; hv[1] = 0; hv[2] = 0; hv[3] = 0; }

            if (valid) {
                short* dst = (g & 2) ? &h2hi[h][widh][0] : &h2lo[h][widh][0];
                *(short4v*)&dst[plc * 8 + (g & 1) * 4] = hv;
            }
        }
    }
    // no barrier: wave consumes only its own h2 region (lgkmcnt-ordered)

    // --- Phase C (wave-private): 4 output rows; 2 chained MFMAs (K=64) + epilogue ---
    {
        short8 a3f0 = *(const short8*)&sW3h[(c16 & 7) * 64 + g * 8];        // k 0..31
        short8 a3f1 = *(const short8*)&sW3h[(c16 & 7) * 64 + 32 + g * 8];   // k 32..63
        if (c16 >= 8) { a3f0 = (short8)0; a3f1 = (short8)0; }               // oc>=8 zero
        const int kwC = g >> 1, ic8 = g & 1;
        const short* h2sel = ic8 ? &h2hi[h][widh][0] : &h2lo[h][widh][0];
        f32x4 bias3;
        float w4r[4];
#pragma unroll
        for (int r = 0; r < 4; ++r) {
            bias3[r] = (g < 2) ? b3[g * 4 + r] : 0.f;
            w4r[r]   = (g < 2) ? w4[g * 4 + r] : 0.f;
        }

        // row-fragment reuse: local rows 0..4 read once each
        short8 bfp = *(const short8*)&h2sel[(c16 + kwC) * 8];
#pragma unroll
        for (int j = 0; j < 4; ++j) {
            short8 bfn = *(const short8*)&h2sel[((j + 1) * 17 + c16 + kwC) * 8];
            f32x4 acc = __builtin_amdgcn_mfma_f32_16x16x32_bf16(a3f0, bfp, bias3, 0, 0, 0);
            acc = __builtin_amdgcn_mfma_f32_16x16x32_bf16(a3f1, bfn, acc, 0, 0, 0);
            bfp = bfn;

            float partial = 0.f;
#pragma unroll
            for (int r = 0; r < 4; ++r) partial = fmaf(prelu(acc[r], a3), w4r[r], partial);
            partial += __shfl_xor(partial, 16, 64);   // oc live only in g=0,1

            if (g == 0) {
                unsigned combined = m2row[j] | m2row[j + 1];   // compile-time j
                unsigned m3 = (combined >> c16) & 3u;

                float outv = m3 ? (partial + b4) : 0.f;
                int y = ty0 + widh * 4 + j, x = tx0 + c16;
                if (y < x) {
                    outv = 0.f;
                } else if (y == x && m3) {
                    outv = fmaxf(outv, 0.f) + log1pf(expf(-fabsf(outv)));
                }
                out[((size_t)bz * N + y) * N + x] = outv;
            }
        }
    }
}

extern "C" void kernel_launch(void* const* d_in, const int* in_sizes, int n_in,
                              void* d_out, int out_size, void* d_ws, size_t ws_size,
                              hipStream_t stream) {
    const float* x    = (const float*)d_in[0];
    const int*   mask = (const int*)  d_in[1];
    const float* w1   = (const float*)d_in[2];
    const float* b1   = (const float*)d_in[3];
    const float* a1   = (const float*)d_in[4];
    const float* w2   = (const float*)d_in[5];
    const float* b2   = (const float*)d_in[6];
    const float* a2   = (const float*)d_in[7];
    const float* w3   = (const float*)d_in[8];
    const float* b3   = (const float*)d_in[9];
    const float* a3   = (const float*)d_in[10];
    const float* w4   = (const float*)d_in[11];
    const float* b4   = (const float*)d_in[12];
    float* out = (float*)d_out;

    dim3 grid(1040, 1, 2);   // 2 lower-triangle tiles per block, parallel halves
    precond_mfma<<<grid, 512, 0, stream>>>(x, mask, w1, b1, a1, w2, b2, a2,
                                           w3, b3, a3, w4, b4, out);
}

// Round 16
// 24.181 us; speedup vs baseline: 1.6993x; 1.0491x over previous
//
#include <hip/hip_runtime.h>
#include <hip/hip_bf16.h>
#include <math.h>

#define N 1024
#define TB 16

typedef __attribute__((ext_vector_type(8))) short short8;
typedef __attribute__((ext_vector_type(4))) short short4v;
typedef __attribute__((ext_vector_type(4))) float f32x4;

// PReLU via max/min: max(v,0) + a*min(v,0)
__device__ __forceinline__ float prelu(float v, float a) {
    return fmaxf(v, 0.f) + a * fminf(v, 0.f);
}

// f32 -> bf16 RNE via hardware cvt (pairs into v_cvt_pk_bf16_f32)
__device__ __forceinline__ short f2bf(float f) {
    return (short)__bfloat16_as_ushort(__float2bfloat16(f));
}

// R16: R14 skeleton (batched early loads, coop Phase A, ONE barrier,
// wave-private B/C) with Phase B re-mapped to row-aligned groups:
//   grp 0..4 : h2 row=grp, cols 0..15  (lr/dx2 compile-time, no /17, no clamp)
//   grp 5    : col 16, rows 0..4       (5 valid lanes)
// Masks: register row-bitmaps m2row[5] + col16bits; zero LDS mask traffic.
__global__ __launch_bounds__(256, 8) void precond_mfma(
    const float* __restrict__ xg, const int* __restrict__ maskg,
    const float* __restrict__ w1, const float* __restrict__ b1, const float* __restrict__ a1p,
    const float* __restrict__ w2, const float* __restrict__ b2, const float* __restrict__ a2p,
    const float* __restrict__ w3, const float* __restrict__ b3, const float* __restrict__ a3p,
    const float* __restrict__ w4, const float* __restrict__ b4p,
    float* __restrict__ out)
{
    const int tid = threadIdx.x;
    const int bz  = blockIdx.z;
    const int t   = blockIdx.x;

    // ---- triangular mapping: t -> (by, bx), bx <= by ----
    int by = (int)((sqrtf(8.0f * (float)t + 1.0f) - 1.0f) * 0.5f);
    while ((by + 1) * (by + 2) / 2 <= t) ++by;
    while (by * (by + 1) / 2 > t) --by;
    const int bx = t - by * (by + 1) / 2;
    const int ty0 = by * TB, tx0 = bx * TB;

    const int lane = tid & 63, wid = tid >> 6;
    const int c16 = lane & 15, g = lane >> 4;

    // ================= EARLY GLOBAL LOADS (all issued up front) =================
    const float w2r0 = w2[tid];
    const float w2r1 = w2[tid + 256];
    const float w3r0 = w3[tid];
    const float w3r1 = w3[tid + 256];

    const int pA0 = tid;
    const int pA1 = tid + 256;
    const bool s1valid = (pA1 < 324);
    const bool s1wave  = ((tid - lane) + 256 < 324);   // waves 0,1
    const int dyA0 = pA0 / 18, dxA0 = pA0 - dyA0 * 18;
    const int dyA1 = pA1 / 18, dxA1 = pA1 - dyA1 * 18;

    int gy0 = ty0 - 1 + dyA0, gx0 = tx0 - 1 + dxA0;
    const bool in0 = (unsigned)gy0 < N && (unsigned)gx0 < N;
    size_t i0 = in0 ? (((size_t)bz * N + gy0) * N + gx0) : 0;
    const int   mr0 = maskg[i0];
    const float xr0 = xg[i0];

    int mr1 = 0; float xr1 = 0.f; bool in1 = false;
    if (s1wave) {
        int gy1 = ty0 - 1 + dyA1, gx1 = tx0 - 1 + dxA1;
        in1 = s1valid && (unsigned)gy1 < N && (unsigned)gx1 < N;
        size_t i1 = in1 ? (((size_t)bz * N + gy1) * N + gx1) : 0;
        mr1 = maskg[i1];
        xr1 = xg[i1];
    }

    // ---- fused zero-fill (closed form): upper tile = (row=bx, col=by+1) ----
    if (by < 63) {
        int zy = bx * TB + (tid >> 4), zx = (by + 1) * TB + (tid & 15);
        out[((size_t)bz * N + zy) * N + zx] = 0.f;   // fire-and-forget
    }

    __shared__ __align__(16) short sW2[512];        // [oc=16][k=32], k = khkw*8 + ic
    __shared__ __align__(16) short sW3h[512];       // [oc=8][k=64],  k = khkw*16 + ic
    __shared__ __align__(16) short h1s[324 * 8];    // [pos 18x18][8ch] bf16
    __shared__ __align__(16) short h2lo[4][85 * 8]; // per-wave: [pos 5x17][ch 0-7]
    __shared__ __align__(16) short h2hi[4][85 * 8]; // per-wave: [pos 5x17][ch 8-15]
    __shared__ __align__(16) unsigned RM1[12];      // 324-bit layer-1 mask bitmap

    const float a1 = a1p[0], a2 = a2p[0], a3 = a3p[0];
    const float b4 = b4p[0];
    const bool leftEdge  = (tx0 == 0);
    const bool rightEdge = (tx0 == N - TB);

    // ---- scatter weights into LDS (consume early loads) ----
    {
        int s0 = tid, s1 = tid + 256;
        sW2[(s0 & ~31) | ((s0 & 3) << 3) | ((s0 >> 2) & 7)] = f2bf(w2r0);
        sW2[(s1 & ~31) | ((s1 & 3) << 3) | ((s1 >> 2) & 7)] = f2bf(w2r1);
        sW3h[(s0 & ~63) | ((s0 & 3) << 4) | ((s0 >> 2) & 15)] = f2bf(w3r0);
        sW3h[(s1 & ~63) | ((s1 & 3) << 4) | ((s1 >> 2) & 15)] = f2bf(w3r1);
    }

    // ---- Phase A: h1 + ballot mask bitmap (consume early loads) ----
    {
        bool mb = in0 && (mr0 > 0);
        float xv = in0 ? xr0 : 0.f;
        unsigned long long bal = __ballot(mb);
        if (lane == 0) *(uint2*)&RM1[2 * wid] = make_uint2((unsigned)bal, (unsigned)(bal >> 32));
        short8 hv;
#pragma unroll
        for (int ch = 0; ch < 8; ++ch) hv[ch] = f2bf(prelu(fmaf(xv, w1[ch], b1[ch]), a1));
        if (!mb) hv = (short8)0;
        *(short8*)&h1s[pA0 * 8] = hv;

        if (s1wave) {
            bool mb1 = in1 && (mr1 > 0);
            float xv1 = in1 ? xr1 : 0.f;
            unsigned long long bal1 = __ballot(mb1);
            if (lane == 0) *(uint2*)&RM1[2 * (wid + 4)] = make_uint2((unsigned)bal1, (unsigned)(bal1 >> 32));
            if (s1valid) {
                short8 hv1;
#pragma unroll
                for (int ch = 0; ch < 8; ++ch) hv1[ch] = f2bf(prelu(fmaf(xv1, w1[ch], b1[ch]), a1));
                if (!mb1) hv1 = (short8)0;
                *(short8*)&h1s[pA1 * 8] = hv1;
            }
        }
    }
    __syncthreads();   // the ONLY barrier

    // ---- per-wave spread masks in registers: m2row[5] (17 bits) + col16bits ----
    unsigned m2row[5];
    unsigned col16bits;
    {
        const int bitbase = 72 * wid;     // 18 * (4*wid)
        unsigned rr[6];
#pragma unroll
        for (int i = 0; i < 6; ++i) {
            int bit = bitbase + 18 * i;
            int w = bit >> 5, sh = bit & 31;
            unsigned long long v = ((unsigned long long)RM1[w + 1] << 32) | RM1[w];
            rr[i] = (unsigned)(v >> sh);
        }
#pragma unroll
        for (int i = 0; i < 5; ++i) {
            unsigned u = rr[i] | rr[i + 1];
            m2row[i] = (u | (u >> 1)) & 0x1FFFFu;
        }
        if (leftEdge) {
#pragma unroll
            for (int i = 0; i < 5; ++i) m2row[i] &= ~1u;
        }
        if (rightEdge) {
#pragma unroll
            for (int i = 0; i < 5; ++i) m2row[i] &= ~(1u << 16);
        }
        col16bits = ((m2row[0] >> 16) & 1u)        | (((m2row[1] >> 16) & 1u) << 1)
                  | (((m2row[2] >> 16) & 1u) << 2) | (((m2row[3] >> 16) & 1u) << 3)
                  | (((m2row[4] >> 16) & 1u) << 4);
    }

    // --- Phase B (wave-private): h2 rows 4w..4w+4, row-aligned groups ---
    {
        short8 a2f = *(const short8*)&sW2[c16 * 32 + g * 8];
        const int kh = g >> 1, kw = g & 1;
        const int rowbase = wid * 4;
        f32x4 bias2;
#pragma unroll
        for (int r = 0; r < 4; ++r) bias2[r] = b2[g * 4 + r];

        short* dst = (g & 2) ? &h2hi[wid][0] : &h2lo[wid][0];
        const int choff = (g & 1) * 4;

        // grp 0..4: row=grp, col=c16 (compile-time lr/dx2; all slots valid)
#pragma unroll
        for (int grp = 0; grp < 5; ++grp) {
            short8 bf = *(const short8*)&h1s[((rowbase + grp + kh) * 18 + c16 + kw) * 8];
            f32x4 acc = __builtin_amdgcn_mfma_f32_16x16x32_bf16(a2f, bf, bias2, 0, 0, 0);
            unsigned m2 = (m2row[grp] >> c16) & 1u;
            short4v hv;
#pragma unroll
            for (int r = 0; r < 4; ++r) hv[r] = f2bf(prelu(acc[r], a2));
            if (m2 == 0) { hv[0] = 0; hv[1] = 0; hv[2] = 0; hv[3] = 0; }
            *(short4v*)&dst[(grp * 17 + c16) * 8 + choff] = hv;
        }
        // grp 5: col 16, row = c16 (valid lanes c16 < 5)
        {
            int lrc = (c16 < 5) ? c16 : 4;
            short8 bf = *(const short8*)&h1s[((rowbase + lrc + kh) * 18 + 16 + kw) * 8];
            f32x4 acc = __builtin_amdgcn_mfma_f32_16x16x32_bf16(a2f, bf, bias2, 0, 0, 0);
            unsigned m2 = (col16bits >> c16) & 1u;   // 0 for c16 >= 5
            short4v hv;
#pragma unroll
            for (int r = 0; r < 4; ++r) hv[r] = f2bf(prelu(acc[r], a2));
            if (m2 == 0) { hv[0] = 0; hv[1] = 0; hv[2] = 0; hv[3] = 0; }
            if (c16 < 5) *(short4v*)&dst[(lrc * 17 + 16) * 8 + choff] = hv;
        }
    }
    // no barrier: wave consumes only its own h2 region (lgkmcnt-ordered)

    // --- Phase C (wave-private): 4 output rows; 2 chained MFMAs (K=64) + epilogue ---
    {
        short8 a3f0 = *(const short8*)&sW3h[(c16 & 7) * 64 + g * 8];        // k 0..31
        short8 a3f1 = *(const short8*)&sW3h[(c16 & 7) * 64 + 32 + g * 8];   // k 32..63
        if (c16 >= 8) { a3f0 = (short8)0; a3f1 = (short8)0; }               // oc>=8 zero
        const int kwC = g >> 1, ic8 = g & 1;
        const short* h2sel = ic8 ? &h2hi[wid][0] : &h2lo[wid][0];
        f32x4 bias3;
        float w4r[4];
#pragma unroll
        for (int r = 0; r < 4; ++r) {
            bias3[r] = (g < 2) ? b3[g * 4 + r] : 0.f;
            w4r[r]   = (g < 2) ? w4[g * 4 + r] : 0.f;
        }

        // row-fragment reuse: local rows 0..4 read once each
        short8 bfp = *(const short8*)&h2sel[(c16 + kwC) * 8];
#pragma unroll
        for (int j = 0; j < 4; ++j) {
            short8 bfn = *(const short8*)&h2sel[((j + 1) * 17 + c16 + kwC) * 8];
            f32x4 acc = __builtin_amdgcn_mfma_f32_16x16x32_bf16(a3f0, bfp, bias3, 0, 0, 0);
            acc = __builtin_amdgcn_mfma_f32_16x16x32_bf16(a3f1, bfn, acc, 0, 0, 0);
            bfp = bfn;

            float partial = 0.f;
#pragma unroll
            for (int r = 0; r < 4; ++r) partial = fmaf(prelu(acc[r], a3), w4r[r], partial);
            partial += __shfl_xor(partial, 16, 64);   // oc live only in g=0,1

            if (g == 0) {
                unsigned combined = m2row[j] | m2row[j + 1];   // compile-time j
                unsigned m3 = (combined >> c16) & 3u;

                float outv = m3 ? (partial + b4) : 0.f;
                int y = ty0 + wid * 4 + j, x = tx0 + c16;
                if (y < x) {
                    outv = 0.f;
                } else if (y == x && m3) {
                    outv = fmaxf(outv, 0.f) + log1pf(expf(-fabsf(outv)));
                }
                out[((size_t)bz * N + y) * N + x] = outv;
            }
        }
    }
}

extern "C" void kernel_launch(void* const* d_in, const int* in_sizes, int n_in,
                              void* d_out, int out_size, void* d_ws, size_t ws_size,
                              hipStream_t stream) {
    const float* x    = (const float*)d_in[0];
    const int*   mask = (const int*)  d_in[1];
    const float* w1   = (const float*)d_in[2];
    const float* b1   = (const float*)d_in[3];
    const float* a1   = (const float*)d_in[4];
    const float* w2   = (const float*)d_in[5];
    const float* b2   = (const float*)d_in[6];
    const float* a2   = (const float*)d_in[7];
    const float* w3   = (const float*)d_in[8];
    const float* b3   = (const float*)d_in[9];
    const float* a3   = (const float*)d_in[10];
    const float* w4   = (const float*)d_in[11];
    const float* b4   = (const float*)d_in[12];
    float* out = (float*)d_out;

    dim3 grid(2080, 1, 2);   // lower-triangle tiles only; zero tiles fused
    precond_mfma<<<grid, 256, 0, stream>>>(x, mask, w1, b1, a1, w2, b2, a2,
                                           w3, b3, a3, w4, b4, out);
}